// Round 9
// baseline (393.927 us; speedup 1.0000x reference)
//
#include <hip/hip_runtime.h>
#include <hip/hip_fp16.h>
#include <stdint.h>

#define K_DIM 4096
#define N_OUT 4096
#define BM 256
#define BN 256
#define BKB 128  // K-bytes per step = 4 MFMA K-slices

typedef __attribute__((ext_vector_type(4))) int int32x4;
typedef __attribute__((ext_vector_type(16))) int int32x16;

// ---------------- per-token int4 activation quantization ----------------
// x_scale = max(x_max/7, fp16(1e-5)); x_q = clip(rint(x/x_scale), -8, 7).
// All f32; no intermediate fp16 rounding (matches harness np reference).
// Output is FRAG-MAJOR xqf: block b = mfrag*128 + kslice (mfrag=row>>5,
// kslice=k>>5), each block 1024B in MFMA lane order:
//   byte[l*16+j] = xq[mfrag*32+(l&31)][kslice*32+((l>>5)<<4)+j]
// Thread t of row `row` holds k=[t*16,t*16+16) -> exactly one 16B slot:
//   dst = mfrag*131072 + (t>>1)*1024 + (t&1)*512 + (row&31)*16
__global__ __launch_bounds__(256) void quant_x(const float* __restrict__ x,
                                               uint8_t* __restrict__ xqf,
                                               float* __restrict__ xs) {
  const int row = blockIdx.x;
  const int t = threadIdx.x;
  const float4* xr = (const float4*)(x + (size_t)row * K_DIM);
  float4 v[4];
  float m = 0.f;
#pragma unroll
  for (int i = 0; i < 4; ++i) {
    v[i] = xr[t * 4 + i];
    m = fmaxf(m, fmaxf(fmaxf(fabsf(v[i].x), fabsf(v[i].y)),
                       fmaxf(fabsf(v[i].z), fabsf(v[i].w))));
  }
#pragma unroll
  for (int off = 32; off > 0; off >>= 1) m = fmaxf(m, __shfl_xor(m, off));
  __shared__ float wmax[4];
  if ((t & 63) == 0) wmax[t >> 6] = m;
  __syncthreads();
  m = fmaxf(fmaxf(wmax[0], wmax[1]), fmaxf(wmax[2], wmax[3]));

  const float eps = 1.0013580322265625e-05f;  // fp16(1e-5) as f32
  const float xscale = fmaxf(m / 7.0f, eps);
  if (t == 0) xs[row] = xscale;

  uint32_t p[4];
#pragma unroll
  for (int g = 0; g < 4; ++g) {
    const float* fv = (const float*)&v[g];
    uint32_t w = 0;
#pragma unroll
    for (int j = 0; j < 4; ++j) {
      float r = rintf(fv[j] / xscale);
      r = fminf(fmaxf(r, -8.f), 7.f);
      w |= ((uint32_t)(uint8_t)(int8_t)(int)r) << (8 * j);
    }
    p[g] = w;
  }
  uint8_t* dst = xqf + (size_t)(row >> 5) * 131072 + (size_t)(t >> 1) * 1024 +
                 (size_t)(t & 1) * 512 + (size_t)(row & 31) * 16;
  *(uint4*)dst = *(uint4*)p;
}

// ---------------- weight pack: int32 -> int8, FRAGMENT-MAJOR ----------------
// block b = nfrag*128 + kslice; each block 1024B in MFMA lane order.
__global__ __launch_bounds__(256) void pack_w(const int* __restrict__ w,
                                              uint32_t* __restrict__ wqf) {
  const int c = blockIdx.x * 256 + threadIdx.x;  // one thread per 16B chunk
  const int blk = c >> 6;
  const int l = c & 63;
  const int row = ((blk >> 7) << 5) + (l & 31);
  const int k = ((blk & 127) << 5) + ((l >> 5) << 4);
  const int4* src = (const int4*)(w + (size_t)row * K_DIM + k);  // 16 ints
  uint32_t p[4];
#pragma unroll
  for (int g = 0; g < 4; ++g) {
    const int4 v = src[g];
    p[g] = (uint32_t)(v.x & 255) | ((uint32_t)(v.y & 255) << 8) |
           ((uint32_t)(v.z & 255) << 16) | ((uint32_t)(v.w & 255) << 24);
  }
  *(uint4*)(wqf + (size_t)c * 4) = *(uint4*)p;
}

// ---------------- i8 GEMM: out = dequant(xq . wq^T) ----------------
// 256x256 tile, 8 waves (2m x 4n, 512 thr), wave tile 128x64, 32x32x32 i8.
// ROLE SWAP vs r8: B (2x read amplification) staged in LDS (32KB/step,
// 2-deep, global_load_lds, frag-major wqf -> linear memcpy); A (4x
// amplification) streams frag-major from global through L1 (1KB contiguous
// frag loads; L1 serves the 4-way reuse). LDS reads halve to 8/wave/step.
// Sync: ONE barrier + vmcnt(0) per step. In-order vmcnt retire => the
// reg-dep wait on the last A-load already retires the earlier B-stages,
// so the vmcnt(0) is nearly free (stages are a full body old).
// a-regs 3-deep (aP/aQ/aR), b-regs 2-deep (bP/bQ), all statically indexed.
__global__ __launch_bounds__(512, 2) void gemm_w4a4(
    const uint8_t* __restrict__ xqf, const uint8_t* __restrict__ wqf,
    const float* __restrict__ xs, const float* __restrict__ wscale,
    float* __restrict__ out, int M) {
  __shared__ uint8_t lds[2][32768];  // B only: 8 nfrag x 4 ks x 1KB per buf

  // Panel-serial XCD swizzle: each XCD owns 4 A-panels consumed serially
  // (1-2 MB A resident in its L2); nt varies fastest within a panel.
  const int bid = blockIdx.x;
  const int xcd = bid & 7;
  const int i_loc = bid >> 3;             // 0..63
  const int nmt = M / BM;                 // 32
  const int mt = xcd * (nmt >> 3) + (i_loc >> 4);  // 0..31
  const int nt = i_loc & 15;              // 0..15
  const int tm = mt * BM;
  const int tn = nt * BN;

  const int t = threadIdx.x;  // 0..511
  const int l = t & 63;
  const int wv = t >> 6;      // 0..7
  const int wm = wv >> 2;     // 0..1
  const int wn = wv & 3;      // 0..3

  // A frag-major base for this wave's 4 m-frags (mfrag0 = mt*8 + wm*4)
  const uint8_t* gAb =
      xqf + (size_t)(mt * 8 + wm * 4) * 131072 + (size_t)l * 16;
  // B staging source: wave wv owns nfrag_local = wv
  const uint8_t* gBs = wqf + (size_t)(nt * 8 + wv) * 131072 + (size_t)l * 16;

  int32x16 acc[4][2] = {};

#define LDA(dst, ksg)                                                        \
  _Pragma("unroll") for (int m_ = 0; m_ < 4; ++m_) dst[m_] =                 \
      *(const int32x4*)(gAb + (size_t)m_ * 131072 + (size_t)(ksg) * 1024);

#define LDB(dst, lb, ks)                                   \
  dst[0] = *(const int32x4*)((lb) + (ks) * 1024);          \
  dst[1] = *(const int32x4*)((lb) + 4096 + (ks) * 1024);

#define MFMA8(A, B)                                                          \
  _Pragma("unroll") for (int m_ = 0; m_ < 4; ++m_) {                         \
    acc[m_][0] = __builtin_amdgcn_mfma_i32_32x32x32_i8(A[m_], B[0],          \
                                                       acc[m_][0], 0, 0, 0); \
    acc[m_][1] = __builtin_amdgcn_mfma_i32_32x32x32_i8(A[m_], B[1],          \
                                                       acc[m_][1], 0, 0, 0); \
  }

  // stage B tile for step ss into buffer buf (4KB per wave, linear copy)
  auto stageB = [&](int buf, int ss) {
    const uint8_t* src = gBs + (size_t)(ss & 31) * 4096;
#pragma unroll
    for (int q = 0; q < 4; ++q) {
      __builtin_amdgcn_global_load_lds(
          (const __attribute__((address_space(1))) uint32_t*)(src + q * 1024),
          (__attribute__((address_space(3))) uint32_t*)(
              &lds[buf][wv * 4096 + q * 1024 + l * 16]),
          16, 0, 0);
    }
  };

  const int nsteps = K_DIM / BKB;  // 32

  // prologue: B(0) into buf0
  stageB(0, 0);
  asm volatile("s_waitcnt vmcnt(0)" ::: "memory");
  __builtin_amdgcn_s_barrier();

  for (int s = 0; s < nsteps; ++s) {
    const int buf = s & 1;
    stageB(buf ^ 1, s + 1);        // 4 x global_load_lds (dead at tail, ok)
    asm volatile("" ::: "memory");  // keep A-loads after B-stages (in-order)
    const int ksg = s * 4;
    const uint8_t* lb = &lds[buf][(wn * 2) * 4096 + l * 16];
    int32x4 aP[4], aQ[4], aR[4], bP[2], bQ[2];
    LDA(aP, ksg + 0);
    LDA(aQ, ksg + 1);
    LDB(bP, lb, 0);
    LDB(bQ, lb, 1);
    LDA(aR, ksg + 2);
    MFMA8(aP, bP);
    LDB(bP, lb, 2);
    LDA(aP, ksg + 3);
    MFMA8(aQ, bQ);
    LDB(bQ, lb, 3);
    MFMA8(aR, bP);
    MFMA8(aP, bQ);
    // outstanding here = B-stages(s+1) only (A drained by MFMA reg-deps,
    // issued after the stages -> in-order retire makes this nearly free)
    asm volatile("s_waitcnt vmcnt(0)" ::: "memory");
    __builtin_amdgcn_s_barrier();
  }

#undef LDA
#undef LDB
#undef MFMA8

  // epilogue: dequant + fp16-round, write f32
  const int colbase = tn + wn * 64;
  const int rowbase = tm + wm * 128 + 4 * (l >> 5);
#pragma unroll
  for (int m = 0; m < 4; ++m) {
#pragma unroll
    for (int n = 0; n < 2; ++n) {
      const int col = colbase + n * 32 + (l & 31);
      const float wsc = wscale[col];
#pragma unroll
      for (int j = 0; j < 16; ++j) {
        const int row = rowbase + m * 32 + (j & 3) + 8 * (j >> 2);
        const float val = (float)acc[m][n][j] * (xs[row] * wsc);
        out[(size_t)row * N_OUT + col] = __half2float(__float2half(val));
      }
    }
  }
}

extern "C" void kernel_launch(void* const* d_in, const int* in_sizes, int n_in,
                              void* d_out, int out_size, void* d_ws, size_t ws_size,
                              hipStream_t stream) {
  const float* x = (const float*)d_in[0];    // fp16 values as f32
  const int* w = (const int*)d_in[1];        // int4-range values as i32
  const float* wsc = (const float*)d_in[2];  // fp16 values as f32
  float* out = (float*)d_out;

  const int M = in_sizes[0] / K_DIM;  // 8192 tokens

  uint8_t* ws = (uint8_t*)d_ws;
  uint8_t* xqf = ws;                                     // M*K bytes (frag-major)
  uint8_t* wqf = ws + (size_t)M * K_DIM;                 // N*K bytes (frag-major)
  float* xs = (float*)(ws + (size_t)M * K_DIM + (size_t)N_OUT * K_DIM);

  quant_x<<<M, 256, 0, stream>>>(x, xqf, xs);
  pack_w<<<(N_OUT * K_DIM / 16) / 256, 256, 0, stream>>>(w, (uint32_t*)wqf);
  gemm_w4a4<<<(M / BM) * (N_OUT / BN), 512, 0, stream>>>(
      xqf, wqf, xs, wsc, out, M);
}

// Round 10
// 217.433 us; speedup vs baseline: 1.8117x; 1.8117x over previous
//
#include <hip/hip_runtime.h>
#include <hip/hip_fp16.h>
#include <stdint.h>

#define K_DIM 4096
#define N_OUT 4096
#define BM 256
#define BN 256
#define BKB 128  // K-bytes per step = 4 MFMA K-slices

typedef __attribute__((ext_vector_type(4))) int int32x4;
typedef __attribute__((ext_vector_type(16))) int int32x16;

// ---------------- per-token int4 activation quantization ----------------
// x_scale = max(x_max/7, fp16(1e-5)); x_q = clip(rint(x/x_scale), -8, 7).
// All f32; no intermediate fp16 rounding (matches harness np reference).
__global__ __launch_bounds__(256) void quant_x(const float* __restrict__ x,
                                               int8_t* __restrict__ xq,
                                               float* __restrict__ xs) {
  const int row = blockIdx.x;
  const int t = threadIdx.x;
  const float4* xr = (const float4*)(x + (size_t)row * K_DIM);
  float4 v[4];
  float m = 0.f;
#pragma unroll
  for (int i = 0; i < 4; ++i) {
    v[i] = xr[t * 4 + i];
    m = fmaxf(m, fmaxf(fmaxf(fabsf(v[i].x), fabsf(v[i].y)),
                       fmaxf(fabsf(v[i].z), fabsf(v[i].w))));
  }
#pragma unroll
  for (int off = 32; off > 0; off >>= 1) m = fmaxf(m, __shfl_xor(m, off));
  __shared__ float wmax[4];
  if ((t & 63) == 0) wmax[t >> 6] = m;
  __syncthreads();
  m = fmaxf(fmaxf(wmax[0], wmax[1]), fmaxf(wmax[2], wmax[3]));

  const float eps = 1.0013580322265625e-05f;  // fp16(1e-5) as f32
  const float xscale = fmaxf(m / 7.0f, eps);
  if (t == 0) xs[row] = xscale;

  uint32_t p[4];
#pragma unroll
  for (int g = 0; g < 4; ++g) {
    const float* fv = (const float*)&v[g];
    uint32_t w = 0;
#pragma unroll
    for (int j = 0; j < 4; ++j) {
      float r = rintf(fv[j] / xscale);
      r = fminf(fmaxf(r, -8.f), 7.f);
      w |= ((uint32_t)(uint8_t)(int8_t)(int)r) << (8 * j);
    }
    p[g] = w;
  }
  *(uint4*)(xq + (size_t)row * K_DIM + t * 16) = *(uint4*)p;
}

// ---------------- weight pack: int32 -> int8, FRAGMENT-MAJOR ----------------
// block b = nfrag*128 + kslice; each block 1024B in MFMA lane order.
__global__ __launch_bounds__(256) void pack_w(const int* __restrict__ w,
                                              uint32_t* __restrict__ wqf) {
  const int c = blockIdx.x * 256 + threadIdx.x;  // one thread per 16B chunk
  const int blk = c >> 6;
  const int l = c & 63;
  const int row = ((blk >> 7) << 5) + (l & 31);
  const int k = ((blk & 127) << 5) + ((l >> 5) << 4);
  const int4* src = (const int4*)(w + (size_t)row * K_DIM + k);  // 16 ints
  uint32_t p[4];
#pragma unroll
  for (int g = 0; g < 4; ++g) {
    const int4 v = src[g];
    p[g] = (uint32_t)(v.x & 255) | ((uint32_t)(v.y & 255) << 8) |
           ((uint32_t)(v.z & 255) << 16) | ((uint32_t)(v.w & 255) << 24);
  }
  *(uint4*)(wqf + (size_t)c * 4) = *(uint4*)p;
}

// ---------------- i8 GEMM: out = dequant(xq . wq^T) ----------------
// 256x256 tile, 8 waves (2m x 4n, 512 thr), wave tile 128x64, 32x32x32 i8.
// A: LDS fragment-contiguous, 3-DEEP pipeline (3x32KB), stage 2 ahead.
// B: fragment-major global -> registers, double-buffered (bX/bY, static).
// r10 deltas vs r8 (165us, MfmaUtil 36%):
//  1. Role stagger: wm=1 waves (SIMD co-wave of wm=0) consume kslices in
//     REVERSE order -> co-waves read opposite LDS regions, MFMA bursts
//     decorrelate. Integer sum order-exact -> identical result.
//  2. setprio(1) around MFMA groups (co-waves now at different phases).
//  3. P=2 prefetch, D=3: staging has 2 full steps to land.
// vmcnt ledger (steady state, end of step s): in-order queue =
// [A(s+1)x4, B(s)x8, A(s+2)x4, B(s+1)x8] = 24 worst-case outstanding;
// vmcnt(20) retires exactly the 4 oldest = A(s+1). Never 0 in the loop.
__global__ __launch_bounds__(512, 2) void gemm_w4a4(
    const int8_t* __restrict__ xq, const uint8_t* __restrict__ wqf,
    const float* __restrict__ xs, const float* __restrict__ wscale,
    float* __restrict__ out, int M) {
  __shared__ uint8_t lds[3][32768];  // A only: 32 frag-blocks (8 fa x 4 ks)/buf

  // Swizzle: A-panels XCD-exclusive (L2-resident); concurrent blocks in an
  // XCD share A via L2.
  const int bid = blockIdx.x;
  const int xcd = bid & 7;
  const int i_loc = bid >> 3;            // 0..63
  const int mt = xcd * 4 + (i_loc & 3);  // 0..31, XCD-exclusive
  const int nt = i_loc >> 2;             // 0..15
  const int tm = mt * BM;
  const int tn = nt * BN;

  const int t = threadIdx.x;  // 0..511
  const int l = t & 63;
  const int wv = t >> 6;      // 0..7
  const int wm = wv >> 2;     // 0..1
  const int wn = wv & 3;      // 0..3

  // A staging source: lane l covers row (l&31), k-bytes (l>>5)*16
  const uint8_t* gA = (const uint8_t*)xq + (size_t)tm * K_DIM +
                      (size_t)(l & 31) * K_DIM + ((l >> 5) << 4);
  // B fragment-major bases for this wave's two n-frags
  const int nfrag0 = nt * 8 + wn * 2;
  const uint8_t* gB0 = wqf + ((size_t)(nfrag0 * 128) << 10) + l * 16;
  const uint8_t* gB1 = wqf + ((size_t)((nfrag0 + 1) * 128) << 10) + l * 16;

  int32x16 acc[4][2] = {};

  // stage quarter q of tile (ktb) into buf: block bIdx = q*8 + wv
  // (fa = bIdx>>2, ks = bIdx&3); LDS dest = q*8192 + t*16 (wave-uniform base
  // + lane*16, as global_load_lds requires).
  auto stageQ = [&](int buf, int ktb, int q) {
    const int bIdx = q * 8 + wv;
    const int fa = bIdx >> 2, ks = bIdx & 3;
    __builtin_amdgcn_global_load_lds(
        (const __attribute__((address_space(1))) uint32_t*)(
            gA + (size_t)(fa * 32) * K_DIM + ks * 32 + ktb),
        (__attribute__((address_space(3))) uint32_t*)(
            &lds[buf][q * 8192 + t * 16]),
        16, 0, 0);
  };

  // load 8 B frags (2 nfrag x 4 ks) for step sw
  auto loadB = [&](int32x4 (&b)[8], int sw) {
#pragma unroll
    for (int ks = 0; ks < 4; ++ks) {
      b[ks] = *(const int32x4*)(gB0 + ((size_t)(sw * 4 + ks) << 10));
      b[4 + ks] = *(const int32x4*)(gB1 + ((size_t)(sw * 4 + ks) << 10));
    }
  };

#define LDA4(dst, base, ks)                                          \
  _Pragma("unroll") for (int m_ = 0; m_ < 4; ++m_) dst[m_] =         \
      *(const int32x4*)((base) + m_ * 4096 + (ks) * 1024);

#define MFMA8(A, B, ks)                                                      \
  __builtin_amdgcn_s_setprio(1);                                             \
  _Pragma("unroll") for (int m_ = 0; m_ < 4; ++m_) {                         \
    acc[m_][0] = __builtin_amdgcn_mfma_i32_32x32x32_i8(A[m_], B[ks],         \
                                                       acc[m_][0], 0, 0, 0); \
    acc[m_][1] = __builtin_amdgcn_mfma_i32_32x32x32_i8(A[m_], B[4 + (ks)],   \
                                                       acc[m_][1], 0, 0, 0); \
  }                                                                          \
  __builtin_amdgcn_s_setprio(0);

#define STEP_BODY(base, B, k0, k1, k2, k3)  \
  {                                         \
    int32x4 a0[4], a1[4];                   \
    LDA4(a0, base, k0);                     \
    LDA4(a1, base, k1);                     \
    MFMA8(a0, B, k0);                       \
    LDA4(a0, base, k2);                     \
    MFMA8(a1, B, k1);                       \
    LDA4(a1, base, k3);                     \
    MFMA8(a0, B, k2);                       \
    MFMA8(a1, B, k3);                       \
  }

  const int nsteps = K_DIM / BKB;  // 32

  // one step: stage A(s+2) into bW, loadB(s+1), compute from bR + bCur.
  auto do_step = [&](int s, int bR, int bW, int32x4 (&bCur)[8],
                     int32x4 (&bNext)[8]) {
#pragma unroll
    for (int q = 0; q < 4; ++q) stageQ(bW, ((s + 2) & 31) * BKB, q);
    asm volatile("" ::: "memory");  // pin order: A-stages before B-loads
    loadB(bNext, (s + 1) & 31);

    const uint8_t* base = &lds[bR][wm * 16384 + l * 16];
    if (wm == 0) {
      STEP_BODY(base, bCur, 0, 1, 2, 3)
    } else {
      STEP_BODY(base, bCur, 3, 2, 1, 0)  // reverse-ks: co-wave decorrelation
    }
    asm volatile("s_waitcnt vmcnt(20)" ::: "memory");  // retire A(s+1)
    __builtin_amdgcn_s_barrier();
  };

  // prologue: A(0)->buf0, A(1)->buf1, B(0)->bX
  int32x4 bX[8], bY[8];
#pragma unroll
  for (int q = 0; q < 4; ++q) stageQ(0, 0, q);
#pragma unroll
  for (int q = 0; q < 4; ++q) stageQ(1, BKB, q);
  asm volatile("" ::: "memory");
  loadB(bX, 0);
  // queue = [A(0)x4, A(1)x4, B(0)x8]; retire A(0)
  asm volatile("s_waitcnt vmcnt(12)" ::: "memory");
  __builtin_amdgcn_s_barrier();

  for (int s = 0; s < nsteps; s += 2) {
    const int m3 = s % 3;  // scalar; buf indices rotate with period 3
    const int r0 = m3, w0 = (m3 + 2) % 3;
    const int r1 = (m3 + 1) % 3, w1 = m3;
    do_step(s, r0, w0, bX, bY);      // consumes bX, prefetches into bY
    do_step(s + 1, r1, w1, bY, bX);  // consumes bY, prefetches into bX
  }
  asm volatile("s_waitcnt vmcnt(0)" ::: "memory");  // drain dead prefetches

#undef LDA4
#undef MFMA8
#undef STEP_BODY

  // epilogue: dequant + fp16-round, write f32
  const int colbase = tn + wn * 64;
  const int rowbase = tm + wm * 128 + 4 * (l >> 5);
#pragma unroll
  for (int m = 0; m < 4; ++m) {
#pragma unroll
    for (int n = 0; n < 2; ++n) {
      const int col = colbase + n * 32 + (l & 31);
      const float wsc = wscale[col];
#pragma unroll
      for (int j = 0; j < 16; ++j) {
        const int row = rowbase + m * 32 + (j & 3) + 8 * (j >> 2);
        const float val = (float)acc[m][n][j] * (xs[row] * wsc);
        out[(size_t)row * N_OUT + col] = __half2float(__float2half(val));
      }
    }
  }
}

extern "C" void kernel_launch(void* const* d_in, const int* in_sizes, int n_in,
                              void* d_out, int out_size, void* d_ws, size_t ws_size,
                              hipStream_t stream) {
  const float* x = (const float*)d_in[0];    // fp16 values as f32
  const int* w = (const int*)d_in[1];        // int4-range values as i32
  const float* wsc = (const float*)d_in[2];  // fp16 values as f32
  float* out = (float*)d_out;

  const int M = in_sizes[0] / K_DIM;  // 8192 tokens

  uint8_t* ws = (uint8_t*)d_ws;
  int8_t* xq = (int8_t*)ws;                              // M*K bytes
  uint8_t* wqf = ws + (size_t)M * K_DIM;                 // N*K bytes (frag-major)
  float* xs = (float*)(ws + (size_t)M * K_DIM + (size_t)N_OUT * K_DIM);

  quant_x<<<M, 256, 0, stream>>>(x, xq, xs);
  pack_w<<<(N_OUT * K_DIM / 16) / 256, 256, 0, stream>>>(w, (uint32_t*)wqf);
  gemm_w4a4<<<(M / BM) * (N_OUT / BN), 512, 0, stream>>>(
      xq, wqf, xs, wsc, out, M);
}